// Round 9
// baseline (452.450 us; speedup 1.0000x reference)
//
#include <hip/hip_runtime.h>
#include <hip/hip_bf16.h>

// Problem constants (match reference setup_inputs)
#define NSETS 8
#define NPTS  4096
#define DF    16
#define KNN   16
#define QG    2                   // query groups per lane (Q=2)
#define QPB   (64 * QG)           // 128 queries per block
#define NWV   16                  // waves per block
#define BLK   1024
#define TILE  1024                // candidates staged into LDS per tile
#define NTILE (NPTS / TILE)       // 4
#define WSLICE (TILE / NWV)       // 64 candidates per wave per tile
#define NEDGE (NSETS * NPTS * KNN)

// Round-9: r8 regressed 2x because Q=2 halved the grid (256 blocks = 1
// block/CU) while 133KB LDS also capped at 1 block -> 8 waves/CU and the
// ds_read->fma chains went unhidden (dur scaled ~1/waves => latency-bound).
// Keep Q=2's halved LDS-reads-per-pair but put 16 waves IN the block:
// BLK=1024, 1 block/CU, 4 waves/SIMD (r7 occupancy + r8 efficiency).
#define RES      5                // reservoir slots/lane/group (1+GRP = 5)
#define FLUSH_AT 2                // flush when any lane cnt >= this
#define GRP      4                // candidates between flush checks

#define FEAT_B   (TILE * DF * 4)             // 65536 B: feat4[4][TILE] transposed
#define NRM_B    (TILE * 4)                  // 4096 B:  nrm_t[TILE]
#define RESV_OFF (FEAT_B + NRM_B)            // 69632
#define RESV_B   (QG * RES * BLK * 8)        // 81920 B
#define SMEM_B   (RESV_OFF + RESV_B)         // 151552 B -> 1 block/CU

__global__ __launch_bounds__(BLK, 1) void knn_kernel(const float* __restrict__ x,
                                                     float* __restrict__ out) {
    __shared__ float tau_sh[QPB];                 // shared per-query tau
    __shared__ __align__(16) char smem[SMEM_B];
    float4* feat4 = (float4*)smem;                // feat4[r*TILE + c], r=0..3
    float*  nrm_t = (float*)(smem + FEAT_B);      // candidate norms
    float2* resvA = (float2*)(smem + RESV_OFF);   // resvA[slot*BLK + t]
    float2* resvB = resvA + RES * BLK;
    // Post-scan overlay (one query-group at a time, 96 KB):
    float*          lds_d = (float*)smem;
    unsigned short* lds_i = (unsigned short*)(smem + BLK * KNN * 4);

    const int t    = threadIdx.x;
    const int lane = t & 63;
    const int wv   = t >> 6;                    // wave 0..15
    const int set  = blockIdx.x >> 5;           // 32 blocks per set
    const int q0   = (blockIdx.x & 31) * QPB;
    const int qa   = q0 + lane;                 // group-A query
    const int qb   = q0 + 64 + lane;            // group-B query

    const float* xs = x + (size_t)set * NPTS * DF;

    if (t < QPB) tau_sh[t] = 3.0e38f;

    // Query features (both groups): q2 via the SAME pairwise tree as candidate
    // norms; qn = -2*q (exact pow2 scale commutes with fma rounding).
    float qnA[DF], qnB[DF];
    float q2A, q2B;
    {
        const float4* qp = (const float4*)(xs + (size_t)qa * DF);
        float4 a = qp[0], b = qp[1], g = qp[2], d = qp[3];
        float r0 = __fadd_rn(__fmul_rn(a.x, a.x), __fmul_rn(g.x, g.x));
        float r1 = __fadd_rn(__fmul_rn(a.y, a.y), __fmul_rn(g.y, g.y));
        float r2 = __fadd_rn(__fmul_rn(a.z, a.z), __fmul_rn(g.z, g.z));
        float r3 = __fadd_rn(__fmul_rn(a.w, a.w), __fmul_rn(g.w, g.w));
        float r4 = __fadd_rn(__fmul_rn(b.x, b.x), __fmul_rn(d.x, d.x));
        float r5 = __fadd_rn(__fmul_rn(b.y, b.y), __fmul_rn(d.y, d.y));
        float r6 = __fadd_rn(__fmul_rn(b.z, b.z), __fmul_rn(d.z, d.z));
        float r7 = __fadd_rn(__fmul_rn(b.w, b.w), __fmul_rn(d.w, d.w));
        q2A = __fadd_rn(__fadd_rn(__fadd_rn(r0, r1), __fadd_rn(r2, r3)),
                        __fadd_rn(__fadd_rn(r4, r5), __fadd_rn(r6, r7)));
        qnA[0]=a.x; qnA[1]=a.y; qnA[2]=a.z; qnA[3]=a.w;
        qnA[4]=b.x; qnA[5]=b.y; qnA[6]=b.z; qnA[7]=b.w;
        qnA[8]=g.x; qnA[9]=g.y; qnA[10]=g.z; qnA[11]=g.w;
        qnA[12]=d.x; qnA[13]=d.y; qnA[14]=d.z; qnA[15]=d.w;
    }
    {
        const float4* qp = (const float4*)(xs + (size_t)qb * DF);
        float4 a = qp[0], b = qp[1], g = qp[2], d = qp[3];
        float r0 = __fadd_rn(__fmul_rn(a.x, a.x), __fmul_rn(g.x, g.x));
        float r1 = __fadd_rn(__fmul_rn(a.y, a.y), __fmul_rn(g.y, g.y));
        float r2 = __fadd_rn(__fmul_rn(a.z, a.z), __fmul_rn(g.z, g.z));
        float r3 = __fadd_rn(__fmul_rn(a.w, a.w), __fmul_rn(g.w, g.w));
        float r4 = __fadd_rn(__fmul_rn(b.x, b.x), __fmul_rn(d.x, d.x));
        float r5 = __fadd_rn(__fmul_rn(b.y, b.y), __fmul_rn(d.y, d.y));
        float r6 = __fadd_rn(__fmul_rn(b.z, b.z), __fmul_rn(d.z, d.z));
        float r7 = __fadd_rn(__fmul_rn(b.w, b.w), __fmul_rn(d.w, d.w));
        q2B = __fadd_rn(__fadd_rn(__fadd_rn(r0, r1), __fadd_rn(r2, r3)),
                        __fadd_rn(__fadd_rn(r4, r5), __fadd_rn(r6, r7)));
        qnB[0]=a.x; qnB[1]=a.y; qnB[2]=a.z; qnB[3]=a.w;
        qnB[4]=b.x; qnB[5]=b.y; qnB[6]=b.z; qnB[7]=b.w;
        qnB[8]=g.x; qnB[9]=g.y; qnB[10]=g.z; qnB[11]=g.w;
        qnB[12]=d.x; qnB[13]=d.y; qnB[14]=d.z; qnB[15]=d.w;
    }
#pragma unroll
    for (int d2 = 0; d2 < DF; ++d2) { qnA[d2] = -2.0f * qnA[d2];
                                      qnB[d2] = -2.0f * qnB[d2]; }

    float LdA[KNN], LdB[KNN];
    int   LiA[KNN], LiB[KNN];
#pragma unroll
    for (int j = 0; j < KNN; ++j) { LdA[j] = 3.0e38f; LiA[j] = 0;
                                    LdB[j] = 3.0e38f; LiB[j] = 0; }
    int cntA = 0, cntB = 0;

    // Exact drain for one group: strict-< shift-insert in append (ascending
    // idx) order, then publish running 16th to that query's shared tau.
    auto flush1 = [&](float2* rb, float (&Ld)[KNN], int (&Li)[KNN],
                      int& cnt, int tidx) {
        for (int e = 0; e < RES; ++e) {
            if (!__any(e < cnt)) break;
            float2 en = rb[e * BLK + t];
            const float d  = (e < cnt) ? en.x : 3.0e38f;
            const int   ci = __float_as_int(en.y);
            if (d < Ld[KNN - 1]) {
#pragma unroll
                for (int j = KNN - 1; j >= 1; --j) {
                    const bool sh   = d < Ld[j - 1];
                    const bool here = d < Ld[j];
                    const float nd = sh ? Ld[j - 1] : (here ? d  : Ld[j]);
                    const int   ni = sh ? Li[j - 1] : (here ? ci : Li[j]);
                    Ld[j] = nd; Li[j] = ni;
                }
                if (d < Ld[0]) { Ld[0] = d; Li[0] = ci; }
            }
        }
        cnt = 0;
        volatile float* ts = (volatile float*)tau_sh;   // benign-race cons. min
        float cur = ts[tidx];
        ts[tidx] = fminf(cur, Ld[KNN - 1]);
    };

    for (int tile = 0; tile < NTILE; ++tile) {
        __syncthreads();   // previous tile fully consumed (covers tau init too)
        {
            const int c = tile * TILE + t;   // thread t stages one candidate
            const float4* p = (const float4*)(xs + (size_t)c * DF);
            float4 a = p[0], b = p[1], g = p[2], d = p[3];
            float r0 = __fadd_rn(__fmul_rn(a.x, a.x), __fmul_rn(g.x, g.x));
            float r1 = __fadd_rn(__fmul_rn(a.y, a.y), __fmul_rn(g.y, g.y));
            float r2 = __fadd_rn(__fmul_rn(a.z, a.z), __fmul_rn(g.z, g.z));
            float r3 = __fadd_rn(__fmul_rn(a.w, a.w), __fmul_rn(g.w, g.w));
            float r4 = __fadd_rn(__fmul_rn(b.x, b.x), __fmul_rn(d.x, d.x));
            float r5 = __fadd_rn(__fmul_rn(b.y, b.y), __fmul_rn(d.y, d.y));
            float r6 = __fadd_rn(__fmul_rn(b.z, b.z), __fmul_rn(d.z, d.z));
            float r7 = __fadd_rn(__fmul_rn(b.w, b.w), __fmul_rn(d.w, d.w));
            feat4[0 * TILE + t] = a;
            feat4[1 * TILE + t] = b;
            feat4[2 * TILE + t] = g;
            feat4[3 * TILE + t] = d;
            nrm_t[t] = __fadd_rn(
                __fadd_rn(__fadd_rn(r0, r1), __fadd_rn(r2, r3)),
                __fadd_rn(__fadd_rn(r4, r5), __fadd_rn(r6, r7)));
        }
        __syncthreads();

        const int lbase = wv * WSLICE;           // local slice base in tile
        const int gbase = tile * TILE + lbase;   // global candidate id base

        for (int g = 0; g < WSLICE; g += GRP) {
            const float tA = fminf(((volatile float*)tau_sh)[lane],
                                   LdA[KNN - 1]);
            const float tB = fminf(((volatile float*)tau_sh)[64 + lane],
                                   LdB[KNN - 1]);
#pragma unroll
            for (int u = 0; u < GRP; ++u) {
                const int lc = lbase + g + u;    // wave-uniform -> broadcast
                float4 f0 = feat4[0 * TILE + lc];
                float4 f1 = feat4[1 * TILE + lc];
                float4 f2 = feat4[2 * TILE + lc];
                float4 f3 = feat4[3 * TILE + lc];
                const float nc = nrm_t[lc];
                float dA = 0.f, dB = 0.f;
                dA = fmaf(qnA[0],  f0.x, dA); dB = fmaf(qnB[0],  f0.x, dB);
                dA = fmaf(qnA[1],  f0.y, dA); dB = fmaf(qnB[1],  f0.y, dB);
                dA = fmaf(qnA[2],  f0.z, dA); dB = fmaf(qnB[2],  f0.z, dB);
                dA = fmaf(qnA[3],  f0.w, dA); dB = fmaf(qnB[3],  f0.w, dB);
                dA = fmaf(qnA[4],  f1.x, dA); dB = fmaf(qnB[4],  f1.x, dB);
                dA = fmaf(qnA[5],  f1.y, dA); dB = fmaf(qnB[5],  f1.y, dB);
                dA = fmaf(qnA[6],  f1.z, dA); dB = fmaf(qnB[6],  f1.z, dB);
                dA = fmaf(qnA[7],  f1.w, dA); dB = fmaf(qnB[7],  f1.w, dB);
                dA = fmaf(qnA[8],  f2.x, dA); dB = fmaf(qnB[8],  f2.x, dB);
                dA = fmaf(qnA[9],  f2.y, dA); dB = fmaf(qnB[9],  f2.y, dB);
                dA = fmaf(qnA[10], f2.z, dA); dB = fmaf(qnB[10], f2.z, dB);
                dA = fmaf(qnA[11], f2.w, dA); dB = fmaf(qnB[11], f2.w, dB);
                dA = fmaf(qnA[12], f3.x, dA); dB = fmaf(qnB[12], f3.x, dB);
                dA = fmaf(qnA[13], f3.y, dA); dB = fmaf(qnB[13], f3.y, dB);
                dA = fmaf(qnA[14], f3.z, dA); dB = fmaf(qnB[14], f3.z, dB);
                dA = fmaf(qnA[15], f3.w, dA); dB = fmaf(qnB[15], f3.w, dB);
                const float distA = __fadd_rn(__fadd_rn(q2A, nc), dA);
                const float distB = __fadd_rn(__fadd_rn(q2B, nc), dB);
                const int ci = gbase + g + u;
                if (distA <= tA) {               // non-strict: keep boundary ties
                    resvA[cntA * BLK + t] = make_float2(distA, __int_as_float(ci));
                    ++cntA;
                }
                if (distB <= tB) {
                    resvB[cntB * BLK + t] = make_float2(distB, __int_as_float(ci));
                    ++cntB;
                }
            }
            if (__any((cntA >= FLUSH_AT) || (cntB >= FLUSH_AT))) {
                flush1(resvA, LdA, LiA, cntA, lane);
                flush1(resvB, LdB, LiB, cntB, 64 + lane);
            }
        }
    }
    flush1(resvA, LdA, LiA, cntA, lane);          // final drains
    flush1(resvB, LdB, LiB, cntB, 64 + lane);

    // ---- Two-pass merge (overlay fits one query-group at a time) -----------
    float* osrc = out;
    float* odst = out + (size_t)NEDGE;
    float* odis = out + 2 * (size_t)NEDGE;

    auto merge16 = [&](int qidx) {   // thread t<64 merges query qidx's 16 lists
        const int ln = t;            // lane within query block (0..63)
        float h[NWV];
        int   hi[NWV];
        int   p[NWV];
#pragma unroll
        for (int w2 = 0; w2 < NWV; ++w2) {
            const int base = (w2 * 64 + ln) * KNN;
            p[w2]  = 0;
            h[w2]  = lds_d[base];
            hi[w2] = (int)lds_i[base];
        }
        const int    gq = set * NPTS + qidx;
        const size_t eb = (size_t)gq * KNN;
        const float srcf = (float)gq;
        for (int e = 0; e < KNN; ++e) {
            float best = h[0];
            int   bi   = hi[0];
            int   bw   = 0;
#pragma unroll
            for (int w2 = 1; w2 < NWV; ++w2) {   // (dist, idx) lexicographic —
                const bool better = (h[w2] < best) ||      // exact stable top-k
                                    (h[w2] == best && hi[w2] < bi);
                if (better) { best = h[w2]; bi = hi[w2]; bw = w2; }
            }
#pragma unroll
            for (int w2 = 0; w2 < NWV; ++w2) {
                if (bw == w2) {
                    ++p[w2];
                    const int base = (w2 * 64 + ln) * KNN;
                    if (p[w2] < KNN) {
                        h[w2]  = lds_d[base + p[w2]];
                        hi[w2] = (int)lds_i[base + p[w2]];
                    } else {
                        h[w2]  = 3.0e38f;
                        hi[w2] = 0x7FFFFFFF;
                    }
                }
            }
            osrc[eb + e] = srcf;
            odst[eb + e] = (float)(set * NPTS + bi);
            odis[eb + e] = best;
        }
    };

    // Pass A
    __syncthreads();   // overlay aliases tile + reservoir regions
#pragma unroll
    for (int j = 0; j < KNN; ++j) {
        lds_d[t * KNN + j] = LdA[j];
        lds_i[t * KNN + j] = (unsigned short)LiA[j];
    }
    __syncthreads();
    if (t < 64) merge16(q0 + t);
    // Pass B
    __syncthreads();
#pragma unroll
    for (int j = 0; j < KNN; ++j) {
        lds_d[t * KNN + j] = LdB[j];
        lds_i[t * KNN + j] = (unsigned short)LiB[j];
    }
    __syncthreads();
    if (t < 64) merge16(q0 + 64 + t);
}

// ---------------------------------------------------------------------------
extern "C" void kernel_launch(void* const* d_in, const int* in_sizes, int n_in,
                              void* d_out, int out_size, void* d_ws, size_t ws_size,
                              hipStream_t stream) {
    (void)in_sizes; (void)n_in; (void)out_size; (void)d_ws; (void)ws_size;
    const float* x = (const float*)d_in[0];  // (8, 4096, 16) f32
    float* out = (float*)d_out;              // [src|dst|dist] f32

    knn_kernel<<<NSETS * (NPTS / QPB), BLK, 0, stream>>>(x, out);
}

// Round 10
// 452.023 us; speedup vs baseline: 1.0009x; 1.0009x over previous
//
#include <hip/hip_runtime.h>
#include <hip/hip_bf16.h>

// Problem constants (match reference setup_inputs)
#define NSETS 8
#define NPTS  4096
#define DF    16
#define KNN   16
#define QG    2                   // query groups per lane (Q=2)
#define QPB   (64 * QG)           // 128 queries per block
#define NWV   16                  // waves per block
#define BLK   1024
#define TILE  1024                // candidates staged into LDS per tile
#define NTILE (NPTS / TILE)       // 4
#define WSLICE (TILE / NWV)       // 64 candidates per wave per tile
#define NEDGE (NSETS * NPTS * KNN)

// Round-10: r9's structure was right (16 waves/CU, Q=2 halves LDS reads/pair)
// but VGPR_Count=64 + WRITE_SIZE 16.6MB exposed a register-spill disaster:
// launch_bounds(1024,1) let the compiler target 8 waves/EU (64 VGPRs) even
// though 148KB LDS caps us at 1 block/CU. Pin waves_per_eu to 4 -> 128-VGPR
// budget, Q=2 state (~116 regs) fits, no scratch traffic. Logic unchanged.
#define RES      5                // reservoir slots/lane/group (1+GRP = 5)
#define FLUSH_AT 2                // flush when any lane cnt >= this
#define GRP      4                // candidates between flush checks

#define FEAT_B   (TILE * DF * 4)             // 65536 B: feat4[4][TILE] transposed
#define NRM_B    (TILE * 4)                  // 4096 B:  nrm_t[TILE]
#define RESV_OFF (FEAT_B + NRM_B)            // 69632
#define RESV_B   (QG * RES * BLK * 8)        // 81920 B
#define SMEM_B   (RESV_OFF + RESV_B)         // 151552 B -> 1 block/CU

__global__ __attribute__((amdgpu_waves_per_eu(4, 4)))
__launch_bounds__(BLK) void knn_kernel(const float* __restrict__ x,
                                       float* __restrict__ out) {
    __shared__ float tau_sh[QPB];                 // shared per-query tau
    __shared__ __align__(16) char smem[SMEM_B];
    float4* feat4 = (float4*)smem;                // feat4[r*TILE + c], r=0..3
    float*  nrm_t = (float*)(smem + FEAT_B);      // candidate norms
    float2* resvA = (float2*)(smem + RESV_OFF);   // resvA[slot*BLK + t]
    float2* resvB = resvA + RES * BLK;
    // Post-scan overlay (one query-group at a time, 96 KB):
    float*          lds_d = (float*)smem;
    unsigned short* lds_i = (unsigned short*)(smem + BLK * KNN * 4);

    const int t    = threadIdx.x;
    const int lane = t & 63;
    const int wv   = t >> 6;                    // wave 0..15
    const int set  = blockIdx.x >> 5;           // 32 blocks per set
    const int q0   = (blockIdx.x & 31) * QPB;
    const int qa   = q0 + lane;                 // group-A query
    const int qb   = q0 + 64 + lane;            // group-B query

    const float* xs = x + (size_t)set * NPTS * DF;

    if (t < QPB) tau_sh[t] = 3.0e38f;

    // Query features (both groups): q2 via the SAME pairwise tree as candidate
    // norms; qn = -2*q (exact pow2 scale commutes with fma rounding).
    float qnA[DF], qnB[DF];
    float q2A, q2B;
    {
        const float4* qp = (const float4*)(xs + (size_t)qa * DF);
        float4 a = qp[0], b = qp[1], g = qp[2], d = qp[3];
        float r0 = __fadd_rn(__fmul_rn(a.x, a.x), __fmul_rn(g.x, g.x));
        float r1 = __fadd_rn(__fmul_rn(a.y, a.y), __fmul_rn(g.y, g.y));
        float r2 = __fadd_rn(__fmul_rn(a.z, a.z), __fmul_rn(g.z, g.z));
        float r3 = __fadd_rn(__fmul_rn(a.w, a.w), __fmul_rn(g.w, g.w));
        float r4 = __fadd_rn(__fmul_rn(b.x, b.x), __fmul_rn(d.x, d.x));
        float r5 = __fadd_rn(__fmul_rn(b.y, b.y), __fmul_rn(d.y, d.y));
        float r6 = __fadd_rn(__fmul_rn(b.z, b.z), __fmul_rn(d.z, d.z));
        float r7 = __fadd_rn(__fmul_rn(b.w, b.w), __fmul_rn(d.w, d.w));
        q2A = __fadd_rn(__fadd_rn(__fadd_rn(r0, r1), __fadd_rn(r2, r3)),
                        __fadd_rn(__fadd_rn(r4, r5), __fadd_rn(r6, r7)));
        qnA[0]=a.x; qnA[1]=a.y; qnA[2]=a.z; qnA[3]=a.w;
        qnA[4]=b.x; qnA[5]=b.y; qnA[6]=b.z; qnA[7]=b.w;
        qnA[8]=g.x; qnA[9]=g.y; qnA[10]=g.z; qnA[11]=g.w;
        qnA[12]=d.x; qnA[13]=d.y; qnA[14]=d.z; qnA[15]=d.w;
    }
    {
        const float4* qp = (const float4*)(xs + (size_t)qb * DF);
        float4 a = qp[0], b = qp[1], g = qp[2], d = qp[3];
        float r0 = __fadd_rn(__fmul_rn(a.x, a.x), __fmul_rn(g.x, g.x));
        float r1 = __fadd_rn(__fmul_rn(a.y, a.y), __fmul_rn(g.y, g.y));
        float r2 = __fadd_rn(__fmul_rn(a.z, a.z), __fmul_rn(g.z, g.z));
        float r3 = __fadd_rn(__fmul_rn(a.w, a.w), __fmul_rn(g.w, g.w));
        float r4 = __fadd_rn(__fmul_rn(b.x, b.x), __fmul_rn(d.x, d.x));
        float r5 = __fadd_rn(__fmul_rn(b.y, b.y), __fmul_rn(d.y, d.y));
        float r6 = __fadd_rn(__fmul_rn(b.z, b.z), __fmul_rn(d.z, d.z));
        float r7 = __fadd_rn(__fmul_rn(b.w, b.w), __fmul_rn(d.w, d.w));
        q2B = __fadd_rn(__fadd_rn(__fadd_rn(r0, r1), __fadd_rn(r2, r3)),
                        __fadd_rn(__fadd_rn(r4, r5), __fadd_rn(r6, r7)));
        qnB[0]=a.x; qnB[1]=a.y; qnB[2]=a.z; qnB[3]=a.w;
        qnB[4]=b.x; qnB[5]=b.y; qnB[6]=b.z; qnB[7]=b.w;
        qnB[8]=g.x; qnB[9]=g.y; qnB[10]=g.z; qnB[11]=g.w;
        qnB[12]=d.x; qnB[13]=d.y; qnB[14]=d.z; qnB[15]=d.w;
    }
#pragma unroll
    for (int d2 = 0; d2 < DF; ++d2) { qnA[d2] = -2.0f * qnA[d2];
                                      qnB[d2] = -2.0f * qnB[d2]; }

    float LdA[KNN], LdB[KNN];
    int   LiA[KNN], LiB[KNN];
#pragma unroll
    for (int j = 0; j < KNN; ++j) { LdA[j] = 3.0e38f; LiA[j] = 0;
                                    LdB[j] = 3.0e38f; LiB[j] = 0; }
    int cntA = 0, cntB = 0;

    // Exact drain for one group: strict-< shift-insert in append (ascending
    // idx) order, then publish running 16th to that query's shared tau.
    auto flush1 = [&](float2* rb, float (&Ld)[KNN], int (&Li)[KNN],
                      int& cnt, int tidx) {
        for (int e = 0; e < RES; ++e) {
            if (!__any(e < cnt)) break;
            float2 en = rb[e * BLK + t];
            const float d  = (e < cnt) ? en.x : 3.0e38f;
            const int   ci = __float_as_int(en.y);
            if (d < Ld[KNN - 1]) {
#pragma unroll
                for (int j = KNN - 1; j >= 1; --j) {
                    const bool sh   = d < Ld[j - 1];
                    const bool here = d < Ld[j];
                    const float nd = sh ? Ld[j - 1] : (here ? d  : Ld[j]);
                    const int   ni = sh ? Li[j - 1] : (here ? ci : Li[j]);
                    Ld[j] = nd; Li[j] = ni;
                }
                if (d < Ld[0]) { Ld[0] = d; Li[0] = ci; }
            }
        }
        cnt = 0;
        volatile float* ts = (volatile float*)tau_sh;   // benign-race cons. min
        float cur = ts[tidx];
        ts[tidx] = fminf(cur, Ld[KNN - 1]);
    };

    for (int tile = 0; tile < NTILE; ++tile) {
        __syncthreads();   // previous tile fully consumed (covers tau init too)
        {
            const int c = tile * TILE + t;   // thread t stages one candidate
            const float4* p = (const float4*)(xs + (size_t)c * DF);
            float4 a = p[0], b = p[1], g = p[2], d = p[3];
            float r0 = __fadd_rn(__fmul_rn(a.x, a.x), __fmul_rn(g.x, g.x));
            float r1 = __fadd_rn(__fmul_rn(a.y, a.y), __fmul_rn(g.y, g.y));
            float r2 = __fadd_rn(__fmul_rn(a.z, a.z), __fmul_rn(g.z, g.z));
            float r3 = __fadd_rn(__fmul_rn(a.w, a.w), __fmul_rn(g.w, g.w));
            float r4 = __fadd_rn(__fmul_rn(b.x, b.x), __fmul_rn(d.x, d.x));
            float r5 = __fadd_rn(__fmul_rn(b.y, b.y), __fmul_rn(d.y, d.y));
            float r6 = __fadd_rn(__fmul_rn(b.z, b.z), __fmul_rn(d.z, d.z));
            float r7 = __fadd_rn(__fmul_rn(b.w, b.w), __fmul_rn(d.w, d.w));
            feat4[0 * TILE + t] = a;
            feat4[1 * TILE + t] = b;
            feat4[2 * TILE + t] = g;
            feat4[3 * TILE + t] = d;
            nrm_t[t] = __fadd_rn(
                __fadd_rn(__fadd_rn(r0, r1), __fadd_rn(r2, r3)),
                __fadd_rn(__fadd_rn(r4, r5), __fadd_rn(r6, r7)));
        }
        __syncthreads();

        const int lbase = wv * WSLICE;           // local slice base in tile
        const int gbase = tile * TILE + lbase;   // global candidate id base

        for (int g = 0; g < WSLICE; g += GRP) {
            const float tA = fminf(((volatile float*)tau_sh)[lane],
                                   LdA[KNN - 1]);
            const float tB = fminf(((volatile float*)tau_sh)[64 + lane],
                                   LdB[KNN - 1]);
#pragma unroll
            for (int u = 0; u < GRP; ++u) {
                const int lc = lbase + g + u;    // wave-uniform -> broadcast
                float4 f0 = feat4[0 * TILE + lc];
                float4 f1 = feat4[1 * TILE + lc];
                float4 f2 = feat4[2 * TILE + lc];
                float4 f3 = feat4[3 * TILE + lc];
                const float nc = nrm_t[lc];
                float dA = 0.f, dB = 0.f;
                dA = fmaf(qnA[0],  f0.x, dA); dB = fmaf(qnB[0],  f0.x, dB);
                dA = fmaf(qnA[1],  f0.y, dA); dB = fmaf(qnB[1],  f0.y, dB);
                dA = fmaf(qnA[2],  f0.z, dA); dB = fmaf(qnB[2],  f0.z, dB);
                dA = fmaf(qnA[3],  f0.w, dA); dB = fmaf(qnB[3],  f0.w, dB);
                dA = fmaf(qnA[4],  f1.x, dA); dB = fmaf(qnB[4],  f1.x, dB);
                dA = fmaf(qnA[5],  f1.y, dA); dB = fmaf(qnB[5],  f1.y, dB);
                dA = fmaf(qnA[6],  f1.z, dA); dB = fmaf(qnB[6],  f1.z, dB);
                dA = fmaf(qnA[7],  f1.w, dA); dB = fmaf(qnB[7],  f1.w, dB);
                dA = fmaf(qnA[8],  f2.x, dA); dB = fmaf(qnB[8],  f2.x, dB);
                dA = fmaf(qnA[9],  f2.y, dA); dB = fmaf(qnB[9],  f2.y, dB);
                dA = fmaf(qnA[10], f2.z, dA); dB = fmaf(qnB[10], f2.z, dB);
                dA = fmaf(qnA[11], f2.w, dA); dB = fmaf(qnB[11], f2.w, dB);
                dA = fmaf(qnA[12], f3.x, dA); dB = fmaf(qnB[12], f3.x, dB);
                dA = fmaf(qnA[13], f3.y, dA); dB = fmaf(qnB[13], f3.y, dB);
                dA = fmaf(qnA[14], f3.z, dA); dB = fmaf(qnB[14], f3.z, dB);
                dA = fmaf(qnA[15], f3.w, dA); dB = fmaf(qnB[15], f3.w, dB);
                const float distA = __fadd_rn(__fadd_rn(q2A, nc), dA);
                const float distB = __fadd_rn(__fadd_rn(q2B, nc), dB);
                const int ci = gbase + g + u;
                if (distA <= tA) {               // non-strict: keep boundary ties
                    resvA[cntA * BLK + t] = make_float2(distA, __int_as_float(ci));
                    ++cntA;
                }
                if (distB <= tB) {
                    resvB[cntB * BLK + t] = make_float2(distB, __int_as_float(ci));
                    ++cntB;
                }
            }
            if (__any((cntA >= FLUSH_AT) || (cntB >= FLUSH_AT))) {
                flush1(resvA, LdA, LiA, cntA, lane);
                flush1(resvB, LdB, LiB, cntB, 64 + lane);
            }
        }
    }
    flush1(resvA, LdA, LiA, cntA, lane);          // final drains
    flush1(resvB, LdB, LiB, cntB, 64 + lane);

    // ---- Two-pass merge (overlay fits one query-group at a time) -----------
    float* osrc = out;
    float* odst = out + (size_t)NEDGE;
    float* odis = out + 2 * (size_t)NEDGE;

    auto merge16 = [&](int qidx) {   // thread t<64 merges query qidx's 16 lists
        const int ln = t;            // lane within query block (0..63)
        float h[NWV];
        int   hi[NWV];
        int   p[NWV];
#pragma unroll
        for (int w2 = 0; w2 < NWV; ++w2) {
            const int base = (w2 * 64 + ln) * KNN;
            p[w2]  = 0;
            h[w2]  = lds_d[base];
            hi[w2] = (int)lds_i[base];
        }
        const int    gq = set * NPTS + qidx;
        const size_t eb = (size_t)gq * KNN;
        const float srcf = (float)gq;
        for (int e = 0; e < KNN; ++e) {
            float best = h[0];
            int   bi   = hi[0];
            int   bw   = 0;
#pragma unroll
            for (int w2 = 1; w2 < NWV; ++w2) {   // (dist, idx) lexicographic —
                const bool better = (h[w2] < best) ||      // exact stable top-k
                                    (h[w2] == best && hi[w2] < bi);
                if (better) { best = h[w2]; bi = hi[w2]; bw = w2; }
            }
#pragma unroll
            for (int w2 = 0; w2 < NWV; ++w2) {
                if (bw == w2) {
                    ++p[w2];
                    const int base = (w2 * 64 + ln) * KNN;
                    if (p[w2] < KNN) {
                        h[w2]  = lds_d[base + p[w2]];
                        hi[w2] = (int)lds_i[base + p[w2]];
                    } else {
                        h[w2]  = 3.0e38f;
                        hi[w2] = 0x7FFFFFFF;
                    }
                }
            }
            osrc[eb + e] = srcf;
            odst[eb + e] = (float)(set * NPTS + bi);
            odis[eb + e] = best;
        }
    };

    // Pass A
    __syncthreads();   // overlay aliases tile + reservoir regions
#pragma unroll
    for (int j = 0; j < KNN; ++j) {
        lds_d[t * KNN + j] = LdA[j];
        lds_i[t * KNN + j] = (unsigned short)LiA[j];
    }
    __syncthreads();
    if (t < 64) merge16(q0 + t);
    // Pass B
    __syncthreads();
#pragma unroll
    for (int j = 0; j < KNN; ++j) {
        lds_d[t * KNN + j] = LdB[j];
        lds_i[t * KNN + j] = (unsigned short)LiB[j];
    }
    __syncthreads();
    if (t < 64) merge16(q0 + 64 + t);
}

// ---------------------------------------------------------------------------
extern "C" void kernel_launch(void* const* d_in, const int* in_sizes, int n_in,
                              void* d_out, int out_size, void* d_ws, size_t ws_size,
                              hipStream_t stream) {
    (void)in_sizes; (void)n_in; (void)out_size; (void)d_ws; (void)ws_size;
    const float* x = (const float*)d_in[0];  // (8, 4096, 16) f32
    float* out = (float*)d_out;              // [src|dst|dist] f32

    knn_kernel<<<NSETS * (NPTS / QPB), BLK, 0, stream>>>(x, out);
}

// Round 11
// 439.491 us; speedup vs baseline: 1.0295x; 1.0285x over previous
//
#include <hip/hip_runtime.h>
#include <hip/hip_bf16.h>

// Problem constants (match reference setup_inputs)
#define NSETS 8
#define NPTS  4096
#define DF    16
#define KNN   16
#define QG    2                   // query groups per lane (Q=2)
#define QPB   (64 * QG)           // 128 queries per block
#define NWV   8                   // waves per block
#define BLK   512
#define HALF  (NPTS / 2)          // 2048 candidates per block (candidate split)
#define TILE  512                 // candidates staged into LDS per tile
#define NTILE (HALF / TILE)       // 4
#define WSLICE (TILE / NWV)       // 64 candidates per wave per tile
#define NEDGE (NSETS * NPTS * KNN)

// Round-11: r9/r10 showed the compiler pins 1024-thread blocks at 64 VGPRs
// (Q=2 state spills ~10MB/launch; waves_per_eu attr ignored). r8 proved
// BLK=512+Q=2 allocates fine (88 VGPRs). Get 16 waves/CU at BLK=512 by
// splitting candidates: grid 512 = (256 query-groups) x (2 halves), 2
// blocks/CU. Each block writes per-(query,half) sorted top-16 packed into
// the query's own 192B output slice (no d_ws): h0 dists->odis, h1 dists->
// osrc, idx u16 pairs->odst. knn_merge_kernel then 2-way merges in place.
#define RES      5                // reservoir slots/lane/group (1+GRP = 5)
#define FLUSH_AT 2                // flush when any lane cnt >= this
#define GRP      4                // candidates between flush checks

#define FEAT_B   (TILE * DF * 4)             // 32768 B: feat4[4][TILE]
#define NRM_B    (TILE * 4)                  // 2048 B
#define RESV_OFF (FEAT_B + NRM_B)            // 34816
#define RESV_B   (QG * RES * BLK * 8)        // 40960 B
#define SMEM_B   (RESV_OFF + RESV_B)         // 75776 B -> 2 blocks/CU

__global__ __launch_bounds__(BLK, 4) void knn_kernel(const float* __restrict__ x,
                                                     float* __restrict__ out) {
    __shared__ float tau_sh[QPB];                 // shared per-query tau
    __shared__ __align__(16) char smem[SMEM_B];
    float4* feat4 = (float4*)smem;                // feat4[r*TILE + c], r=0..3
    float*  nrm_t = (float*)(smem + FEAT_B);      // candidate norms
    float2* resvA = (float2*)(smem + RESV_OFF);   // resvA[slot*BLK + t]
    float2* resvB = resvA + RES * BLK;
    // Post-scan overlay (one query-group at a time, 48 KB):
    float*          lds_d = (float*)smem;
    unsigned short* lds_i = (unsigned short*)(smem + BLK * KNN * 4);

    const int t    = threadIdx.x;
    const int lane = t & 63;
    const int wv   = t >> 6;                    // wave 0..7
    const int grp  = blockIdx.x >> 1;           // query group 0..255
    const int half = blockIdx.x & 1;            // candidate half
    const int set  = grp >> 5;                  // 32 groups per set
    const int q0   = (grp & 31) * QPB;          // set-relative base query
    const int qa   = q0 + lane;                 // group-A query (set-rel)
    const int qb   = q0 + 64 + lane;            // group-B query (set-rel)

    const float* xs = x + (size_t)set * NPTS * DF;

    if (t < QPB) tau_sh[t] = 3.0e38f;

    // Query features (both groups): q2 via the SAME pairwise tree as candidate
    // norms; qn = -2*q (exact pow2 scale commutes with fma rounding).
    float qnA[DF], qnB[DF];
    float q2A, q2B;
    {
        const float4* qp = (const float4*)(xs + (size_t)qa * DF);
        float4 a = qp[0], b = qp[1], g = qp[2], d = qp[3];
        float r0 = __fadd_rn(__fmul_rn(a.x, a.x), __fmul_rn(g.x, g.x));
        float r1 = __fadd_rn(__fmul_rn(a.y, a.y), __fmul_rn(g.y, g.y));
        float r2 = __fadd_rn(__fmul_rn(a.z, a.z), __fmul_rn(g.z, g.z));
        float r3 = __fadd_rn(__fmul_rn(a.w, a.w), __fmul_rn(g.w, g.w));
        float r4 = __fadd_rn(__fmul_rn(b.x, b.x), __fmul_rn(d.x, d.x));
        float r5 = __fadd_rn(__fmul_rn(b.y, b.y), __fmul_rn(d.y, d.y));
        float r6 = __fadd_rn(__fmul_rn(b.z, b.z), __fmul_rn(d.z, d.z));
        float r7 = __fadd_rn(__fmul_rn(b.w, b.w), __fmul_rn(d.w, d.w));
        q2A = __fadd_rn(__fadd_rn(__fadd_rn(r0, r1), __fadd_rn(r2, r3)),
                        __fadd_rn(__fadd_rn(r4, r5), __fadd_rn(r6, r7)));
        qnA[0]=a.x; qnA[1]=a.y; qnA[2]=a.z; qnA[3]=a.w;
        qnA[4]=b.x; qnA[5]=b.y; qnA[6]=b.z; qnA[7]=b.w;
        qnA[8]=g.x; qnA[9]=g.y; qnA[10]=g.z; qnA[11]=g.w;
        qnA[12]=d.x; qnA[13]=d.y; qnA[14]=d.z; qnA[15]=d.w;
    }
    {
        const float4* qp = (const float4*)(xs + (size_t)qb * DF);
        float4 a = qp[0], b = qp[1], g = qp[2], d = qp[3];
        float r0 = __fadd_rn(__fmul_rn(a.x, a.x), __fmul_rn(g.x, g.x));
        float r1 = __fadd_rn(__fmul_rn(a.y, a.y), __fmul_rn(g.y, g.y));
        float r2 = __fadd_rn(__fmul_rn(a.z, a.z), __fmul_rn(g.z, g.z));
        float r3 = __fadd_rn(__fmul_rn(a.w, a.w), __fmul_rn(g.w, g.w));
        float r4 = __fadd_rn(__fmul_rn(b.x, b.x), __fmul_rn(d.x, d.x));
        float r5 = __fadd_rn(__fmul_rn(b.y, b.y), __fmul_rn(d.y, d.y));
        float r6 = __fadd_rn(__fmul_rn(b.z, b.z), __fmul_rn(d.z, d.z));
        float r7 = __fadd_rn(__fmul_rn(b.w, b.w), __fmul_rn(d.w, d.w));
        q2B = __fadd_rn(__fadd_rn(__fadd_rn(r0, r1), __fadd_rn(r2, r3)),
                        __fadd_rn(__fadd_rn(r4, r5), __fadd_rn(r6, r7)));
        qnB[0]=a.x; qnB[1]=a.y; qnB[2]=a.z; qnB[3]=a.w;
        qnB[4]=b.x; qnB[5]=b.y; qnB[6]=b.z; qnB[7]=b.w;
        qnB[8]=g.x; qnB[9]=g.y; qnB[10]=g.z; qnB[11]=g.w;
        qnB[12]=d.x; qnB[13]=d.y; qnB[14]=d.z; qnB[15]=d.w;
    }
#pragma unroll
    for (int d2 = 0; d2 < DF; ++d2) { qnA[d2] = -2.0f * qnA[d2];
                                      qnB[d2] = -2.0f * qnB[d2]; }

    float LdA[KNN], LdB[KNN];
    int   LiA[KNN], LiB[KNN];
#pragma unroll
    for (int j = 0; j < KNN; ++j) { LdA[j] = 3.0e38f; LiA[j] = 0;
                                    LdB[j] = 3.0e38f; LiB[j] = 0; }
    int cntA = 0, cntB = 0;

    // Exact drain: strict-< shift-insert in append (ascending idx) order,
    // then publish running 16th to that query's shared tau.
    auto flush1 = [&](float2* rb, float (&Ld)[KNN], int (&Li)[KNN],
                      int& cnt, int tidx) {
        for (int e = 0; e < RES; ++e) {
            if (!__any(e < cnt)) break;
            float2 en = rb[e * BLK + t];
            const float d  = (e < cnt) ? en.x : 3.0e38f;
            const int   ci = __float_as_int(en.y);
            if (d < Ld[KNN - 1]) {
#pragma unroll
                for (int j = KNN - 1; j >= 1; --j) {
                    const bool sh   = d < Ld[j - 1];
                    const bool here = d < Ld[j];
                    const float nd = sh ? Ld[j - 1] : (here ? d  : Ld[j]);
                    const int   ni = sh ? Li[j - 1] : (here ? ci : Li[j]);
                    Ld[j] = nd; Li[j] = ni;
                }
                if (d < Ld[0]) { Ld[0] = d; Li[0] = ci; }
            }
        }
        cnt = 0;
        volatile float* ts = (volatile float*)tau_sh;   // benign-race cons. min
        float cur = ts[tidx];
        ts[tidx] = fminf(cur, Ld[KNN - 1]);
    };

    for (int tile = 0; tile < NTILE; ++tile) {
        __syncthreads();   // previous tile fully consumed (covers tau init too)
        {
            const int c = half * HALF + tile * TILE + t;   // set-relative cand
            const float4* p = (const float4*)(xs + (size_t)c * DF);
            float4 a = p[0], b = p[1], g = p[2], d = p[3];
            float r0 = __fadd_rn(__fmul_rn(a.x, a.x), __fmul_rn(g.x, g.x));
            float r1 = __fadd_rn(__fmul_rn(a.y, a.y), __fmul_rn(g.y, g.y));
            float r2 = __fadd_rn(__fmul_rn(a.z, a.z), __fmul_rn(g.z, g.z));
            float r3 = __fadd_rn(__fmul_rn(a.w, a.w), __fmul_rn(g.w, g.w));
            float r4 = __fadd_rn(__fmul_rn(b.x, b.x), __fmul_rn(d.x, d.x));
            float r5 = __fadd_rn(__fmul_rn(b.y, b.y), __fmul_rn(d.y, d.y));
            float r6 = __fadd_rn(__fmul_rn(b.z, b.z), __fmul_rn(d.z, d.z));
            float r7 = __fadd_rn(__fmul_rn(b.w, b.w), __fmul_rn(d.w, d.w));
            feat4[0 * TILE + t] = a;
            feat4[1 * TILE + t] = b;
            feat4[2 * TILE + t] = g;
            feat4[3 * TILE + t] = d;
            nrm_t[t] = __fadd_rn(
                __fadd_rn(__fadd_rn(r0, r1), __fadd_rn(r2, r3)),
                __fadd_rn(__fadd_rn(r4, r5), __fadd_rn(r6, r7)));
        }
        __syncthreads();

        const int lbase = wv * WSLICE;
        const int gbase = half * HALF + tile * TILE + lbase;  // set-rel id base

        for (int g = 0; g < WSLICE; g += GRP) {
            const float tA = fminf(((volatile float*)tau_sh)[lane],
                                   LdA[KNN - 1]);
            const float tB = fminf(((volatile float*)tau_sh)[64 + lane],
                                   LdB[KNN - 1]);
#pragma unroll
            for (int u = 0; u < GRP; ++u) {
                const int lc = lbase + g + u;    // wave-uniform -> broadcast
                float4 f0 = feat4[0 * TILE + lc];
                float4 f1 = feat4[1 * TILE + lc];
                float4 f2 = feat4[2 * TILE + lc];
                float4 f3 = feat4[3 * TILE + lc];
                const float nc = nrm_t[lc];
                float dA = 0.f, dB = 0.f;
                dA = fmaf(qnA[0],  f0.x, dA); dB = fmaf(qnB[0],  f0.x, dB);
                dA = fmaf(qnA[1],  f0.y, dA); dB = fmaf(qnB[1],  f0.y, dB);
                dA = fmaf(qnA[2],  f0.z, dA); dB = fmaf(qnB[2],  f0.z, dB);
                dA = fmaf(qnA[3],  f0.w, dA); dB = fmaf(qnB[3],  f0.w, dB);
                dA = fmaf(qnA[4],  f1.x, dA); dB = fmaf(qnB[4],  f1.x, dB);
                dA = fmaf(qnA[5],  f1.y, dA); dB = fmaf(qnB[5],  f1.y, dB);
                dA = fmaf(qnA[6],  f1.z, dA); dB = fmaf(qnB[6],  f1.z, dB);
                dA = fmaf(qnA[7],  f1.w, dA); dB = fmaf(qnB[7],  f1.w, dB);
                dA = fmaf(qnA[8],  f2.x, dA); dB = fmaf(qnB[8],  f2.x, dB);
                dA = fmaf(qnA[9],  f2.y, dA); dB = fmaf(qnB[9],  f2.y, dB);
                dA = fmaf(qnA[10], f2.z, dA); dB = fmaf(qnB[10], f2.z, dB);
                dA = fmaf(qnA[11], f2.w, dA); dB = fmaf(qnB[11], f2.w, dB);
                dA = fmaf(qnA[12], f3.x, dA); dB = fmaf(qnB[12], f3.x, dB);
                dA = fmaf(qnA[13], f3.y, dA); dB = fmaf(qnB[13], f3.y, dB);
                dA = fmaf(qnA[14], f3.z, dA); dB = fmaf(qnB[14], f3.z, dB);
                dA = fmaf(qnA[15], f3.w, dA); dB = fmaf(qnB[15], f3.w, dB);
                const float distA = __fadd_rn(__fadd_rn(q2A, nc), dA);
                const float distB = __fadd_rn(__fadd_rn(q2B, nc), dB);
                const int ci = gbase + g + u;
                if (distA <= tA) {               // non-strict: keep boundary ties
                    resvA[cntA * BLK + t] = make_float2(distA, __int_as_float(ci));
                    ++cntA;
                }
                if (distB <= tB) {
                    resvB[cntB * BLK + t] = make_float2(distB, __int_as_float(ci));
                    ++cntB;
                }
            }
            if (__any((cntA >= FLUSH_AT) || (cntB >= FLUSH_AT))) {
                flush1(resvA, LdA, LiA, cntA, lane);
                flush1(resvB, LdB, LiB, cntB, 64 + lane);
            }
        }
    }
    flush1(resvA, LdA, LiA, cntA, lane);          // final drains
    flush1(resvB, LdB, LiB, cntB, 64 + lane);

    // ---- Merge 8 per-wave lists per query; emit packed intermediate --------
    float* osrc = out;
    float* odst = out + (size_t)NEDGE;
    float* odis = out + 2 * (size_t)NEDGE;
    unsigned short* pidx = (unsigned short*)odst;  // u16 idx store region

    auto merge8_store = [&](int qs) {  // thread t<64 merges query qs (set-rel)
        const int ln = t;
        float h[NWV];
        int   hi[NWV];
        int   p[NWV];
#pragma unroll
        for (int w2 = 0; w2 < NWV; ++w2) {
            const int base = (w2 * 64 + ln) * KNN;
            p[w2]  = 0;
            h[w2]  = lds_d[base];
            hi[w2] = (int)lds_i[base];
        }
        const int gq = (set << 12) + qs;
        for (int e = 0; e < KNN; ++e) {
            float best = h[0];
            int   bi   = hi[0];
            int   bw   = 0;
#pragma unroll
            for (int w2 = 1; w2 < NWV; ++w2) {   // (dist, idx) lexicographic
                const bool better = (h[w2] < best) ||
                                    (h[w2] == best && hi[w2] < bi);
                if (better) { best = h[w2]; bi = hi[w2]; bw = w2; }
            }
#pragma unroll
            for (int w2 = 0; w2 < NWV; ++w2) {
                if (bw == w2) {
                    ++p[w2];
                    const int base = (w2 * 64 + ln) * KNN;
                    if (p[w2] < KNN) {
                        h[w2]  = lds_d[base + p[w2]];
                        hi[w2] = (int)lds_i[base + p[w2]];
                    } else {
                        h[w2]  = 3.0e38f;
                        hi[w2] = 0x7FFFFFFF;
                    }
                }
            }
            // Packed intermediate in this query's own 192B output slice:
            if (half == 0) {
                odis[(size_t)gq * KNN + e] = best;
                pidx[(size_t)gq * 32 + e] = (unsigned short)bi;
            } else {
                osrc[(size_t)gq * KNN + e] = best;
                pidx[(size_t)gq * 32 + 16 + e] = (unsigned short)bi;
            }
        }
    };

    // Pass A
    __syncthreads();   // overlay aliases tile + reservoir regions
#pragma unroll
    for (int j = 0; j < KNN; ++j) {
        lds_d[t * KNN + j] = LdA[j];
        lds_i[t * KNN + j] = (unsigned short)LiA[j];
    }
    __syncthreads();
    if (t < 64) merge8_store(q0 + t);
    // Pass B
    __syncthreads();
#pragma unroll
    for (int j = 0; j < KNN; ++j) {
        lds_d[t * KNN + j] = LdB[j];
        lds_i[t * KNN + j] = (unsigned short)LiB[j];
    }
    __syncthreads();
    if (t < 64) merge8_store(q0 + 64 + t);
}

// ---------------------------------------------------------------------------
// Kernel 2: per-query in-place 2-way merge of the two packed sorted 16-lists.
// Thread = query; reads only its own 192B slice, writes only its own slice.
__global__ __launch_bounds__(256) void knn_merge_kernel(float* __restrict__ out) {
    __shared__ float          sd[256][32];
    __shared__ unsigned short si[256][32];
    const int lt = threadIdx.x;
    const int gq = blockIdx.x * 256 + lt;      // global query id
    const int set = gq >> 12;

    float* osrc = out;
    float* odst = out + (size_t)NEDGE;
    float* odis = out + 2 * (size_t)NEDGE;
    const unsigned short* pidx = (const unsigned short*)odst;

#pragma unroll
    for (int e = 0; e < KNN; ++e) {
        sd[lt][e]       = odis[(size_t)gq * KNN + e];   // half-0 dists
        sd[lt][16 + e]  = osrc[(size_t)gq * KNN + e];   // half-1 dists
        si[lt][e]       = pidx[(size_t)gq * 32 + e];        // half-0 idx
        si[lt][16 + e]  = pidx[(size_t)gq * 32 + 16 + e];   // half-1 idx
    }

    // 2-pointer merge, (dist, idx) lexicographic. p0+p1==e<16 so p0,p1<=15:
    // in-range without guards (h0 idx in [0,2048), h1 in [2048,4096)).
    int p0 = 0, p1 = 0;
    float rd[KNN];
    int   ri[KNN];
#pragma unroll
    for (int e = 0; e < KNN; ++e) {
        const float da = sd[lt][p0];
        const float db = sd[lt][16 + p1];
        const int   ia = (int)si[lt][p0];
        const int   ib = (int)si[lt][16 + p1];
        const bool t0 = (da < db) || (da == db && ia < ib);
        rd[e] = t0 ? da : db;
        ri[e] = t0 ? ia : ib;
        p0 += t0 ? 1 : 0;
        p1 += t0 ? 0 : 1;
    }

    const float srcf = (float)gq;
#pragma unroll
    for (int e = 0; e < KNN; ++e) {
        osrc[(size_t)gq * KNN + e] = srcf;
        odst[(size_t)gq * KNN + e] = (float)((set << 12) + ri[e]);
        odis[(size_t)gq * KNN + e] = rd[e];
    }
}

// ---------------------------------------------------------------------------
extern "C" void kernel_launch(void* const* d_in, const int* in_sizes, int n_in,
                              void* d_out, int out_size, void* d_ws, size_t ws_size,
                              hipStream_t stream) {
    (void)in_sizes; (void)n_in; (void)out_size; (void)d_ws; (void)ws_size;
    const float* x = (const float*)d_in[0];  // (8, 4096, 16) f32
    float* out = (float*)d_out;              // [src|dst|dist] f32

    knn_kernel<<<NSETS * 32 * 2, BLK, 0, stream>>>(x, out);
    knn_merge_kernel<<<(NSETS * NPTS) / 256, 256, 0, stream>>>(out);
}